// Round 2
// baseline (89.238 us; speedup 1.0000x reference)
//
#include <hip/hip_runtime.h>
#include <hip/hip_bf16.h>

// Disable FP contraction so every multiply/add rounds exactly like the
// numpy/JAX f32 reference (FMA fusion would change discrete voxel coords
// and flip ray_valid bits, which must be exact).
#pragma clang fp contract(off)

#define NRAYS 16384
#define NSAMP 512

typedef __attribute__((ext_vector_type(4))) float floatx4;

static __device__ __forceinline__ unsigned int expand_bits(unsigned int v) {
    v = (v * 65537u) & 4278190335u;
    v = (v * 257u)   & 251719695u;
    v = (v * 17u)    & 3272356035u;
    v = (v * 5u)     & 1227133513u;
    return v;
}

__global__ __launch_bounds__(256) void ca_kernel(
    const float* __restrict__ rays_chunk,
    const float* __restrict__ jitter,
    const int*   __restrict__ bitfield,
    float* __restrict__ out)
{
#pragma clang fp contract(off)
    const int tid = blockIdx.x * 256 + threadIdx.x;
    const int ray = tid >> 6;          // 64 threads (one wave) per ray
    const int s0  = (tid & 63) << 3;   // 8 samples per thread

    // Constants: computed in f64 exactly like Python, then cast to f32.
    const float STEP  = (float)((6.0 - 0.2) / 512.0);
    const float HALFS = (float)(((6.0 - 0.2) / 512.0) / 2.0);
    const float C415  = (float)(4.0 / 15.0);
    const float C512  = (float)(5.0 / 12.0);
    const double br   = 0.0008 * 2.0 / __builtin_sqrt(12.0);
    const float BR2   = (float)(br * br);
    const float DIVB  = 1.984375f;     // BOUND - half_grid, exact in f32

    const float* rp = rays_chunk + ray * 6;
    const float ox = rp[0], oy = rp[1], oz = rp[2];
    const float dx = rp[3], dy = rp[4], dz = rp[5];

    // Per-ray null_diag (matches: d_sq, d_mag_sq = max((x+y)+z, 1e-10))
    const float dsx = dx * dx, dsy = dy * dy, dsz = dz * dz;
    float dms = (dsx + dsy) + dsz;
    dms = fmaxf(dms, 1e-10f);
    const float nlx = 1.0f - dsx / dms;
    const float nly = 1.0f - dsy / dms;
    const float nlz = 1.0f - dsz / dms;

    const int sbase = ray * NSAMP + s0;
    const floatx4 j0 = *reinterpret_cast<const floatx4*>(jitter + sbase);
    const floatx4 j1 = *reinterpret_cast<const floatx4*>(jitter + sbase + 4);
    float jloc[9];
    jloc[0] = j0[0]; jloc[1] = j0[1]; jloc[2] = j0[2]; jloc[3] = j0[3];
    jloc[4] = j1[0]; jloc[5] = j1[1]; jloc[6] = j1[2]; jloc[7] = j1[3];
    jloc[8] = (s0 + 8 < NSAMP) ? jitter[sbase + 8] : 0.0f;

    float vsv[8], zsv[8], dsv[8];
    floatx4* xout = reinterpret_cast<floatx4*>(out + (size_t)sbase * 4);

#pragma unroll
    for (int i = 0; i < 8; ++i) {
        const float fs = (float)(s0 + i);
        const float z  = 0.2f + STEP * (fs + jloc[i]);
        const float t0 = z - HALFS;
        const float t1 = t0 + HALFS;
        const float mu = (t0 + t1) / 2.0f;
        const float hw = (t1 - t0) / 2.0f;
        const float mu2 = mu * mu;
        const float hw2 = hw * hw;
        const float hw4 = hw2 * hw2;
        const float denom  = 3.0f * mu2 + hw2;
        const float t_mean = mu + ((2.0f * mu) * hw2) / denom;
        const float inner  = 12.0f * mu2 - hw2;
        const float denom2 = denom * denom;
        const float t_var  = hw2 / 3.0f - (C415 * (hw4 * inner)) / denom2;
        const float r_var  = BR2 * ((mu2 / 4.0f + C512 * hw2) - (C415 * hw4) / denom);

        const float px = ox + dx * t_mean;
        const float py = oy + dy * t_mean;
        const float pz = oz + dz * t_mean;

        const bool outb = (px < -2.0f) | (px > 2.0f) |
                          (py < -2.0f) | (py > 2.0f) |
                          (pz < -2.0f) | (pz > 2.0f);

        const float vx = t_var * dsx + r_var * nlx;
        const float vy = t_var * dsy + r_var * nly;
        const float vz = t_var * dsz + r_var * nlz;
        const float vmax = fmaxf(fmaxf(vx, vy), vz);

        // voxel coords — exact reference op order
        const float cxn = fminf(fmaxf(px / DIVB, -1.0f), 1.0f);
        const float cyn = fminf(fmaxf(py / DIVB, -1.0f), 1.0f);
        const float czn = fminf(fmaxf(pz / DIVB, -1.0f), 1.0f);
        const float cfx = fminf(fmaxf((cxn + 1.0f) / 2.0f * 127.0f, 0.0f), 127.0f);
        const float cfy = fminf(fmaxf((cyn + 1.0f) / 2.0f * 127.0f, 0.0f), 127.0f);
        const float cfz = fminf(fmaxf((czn + 1.0f) / 2.0f * 127.0f, 0.0f), 127.0f);
        const unsigned int ux = (unsigned int)cfx;
        const unsigned int uy = (unsigned int)cfy;
        const unsigned int uz = (unsigned int)cfz;
        unsigned int m = expand_bits(ux) | (expand_bits(uy) << 1) | (expand_bits(uz) << 2);
        if (m > 2097151u) m = 2097151u;
        const int byte = bitfield[m >> 3];
        const bool alpha = ((byte >> (int)(m & 7u)) & 1) != 0;
        const bool valid = (!outb) && alpha;

        // next z (bit-identical recomputation) for dists
        const float jn = (i < 7) ? jloc[i + 1] : jloc[8];
        const float zn = 0.2f + STEP * ((fs + 1.0f) + jn);
        const float dist = (s0 + i < NSAMP - 1) ? (zn - z) : 0.0f;

        floatx4 xw;
        xw[0] = px; xw[1] = py; xw[2] = pz; xw[3] = vmax;
        xout[i] = xw;

        vsv[i] = valid ? 1.0f : 0.0f;
        zsv[i] = z;
        dsv[i] = dist;
    }

    const size_t OFF_VALID = (size_t)NRAYS * NSAMP * 4;             // 33554432
    const size_t OFF_Z     = OFF_VALID + (size_t)NRAYS * NSAMP;     // 41943040
    const size_t OFF_D     = OFF_Z     + (size_t)NRAYS * NSAMP;     // 50331648

    floatx4* vout = reinterpret_cast<floatx4*>(out + OFF_VALID + sbase);
    floatx4* zout = reinterpret_cast<floatx4*>(out + OFF_Z     + sbase);
    floatx4* dout = reinterpret_cast<floatx4*>(out + OFF_D     + sbase);
#pragma unroll
    for (int k = 0; k < 2; ++k) {
        floatx4 wv, wz, wd;
#pragma unroll
        for (int e = 0; e < 4; ++e) {
            wv[e] = vsv[4*k + e];
            wz[e] = zsv[4*k + e];
            wd[e] = dsv[4*k + e];
        }
        vout[k] = wv;
        zout[k] = wz;
        dout[k] = wd;
    }
}

extern "C" void kernel_launch(void* const* d_in, const int* in_sizes, int n_in,
                              void* d_out, int out_size, void* d_ws, size_t ws_size,
                              hipStream_t stream) {
    const float* rays = (const float*)d_in[0];
    const float* jit  = (const float*)d_in[1];
    const int*   bf   = (const int*)d_in[2];
    float* out = (float*)d_out;

    const int total_threads = NRAYS * NSAMP / 8;   // 1,048,576
    dim3 grid(total_threads / 256), block(256);
    hipLaunchKernelGGL(ca_kernel, grid, block, 0, stream, rays, jit, bf, out);
}

// Round 3
// 65.362 us; speedup vs baseline: 1.3653x; 1.3653x over previous
//
#include <hip/hip_runtime.h>
#include <hip/hip_bf16.h>

// Disable FP contraction so every multiply/add rounds exactly like the
// numpy/JAX f32 reference (FMA fusion would change discrete voxel coords
// and flip ray_valid bits, which must be exact).
#pragma clang fp contract(off)

#define NRAYS 16384
#define NSAMP 512

typedef __attribute__((ext_vector_type(4))) float floatx4;

static __device__ __forceinline__ unsigned int expand_bits(unsigned int v) {
    v = (v * 65537u) & 4278190335u;
    v = (v * 257u)   & 251719695u;
    v = (v * 17u)    & 3272356035u;
    v = (v * 5u)     & 1227133513u;
    return v;
}

__global__ __launch_bounds__(256) void ca_kernel(
    const float* __restrict__ rays_chunk,
    const float* __restrict__ jitter,
    const int*   __restrict__ bitfield,
    float* __restrict__ out)
{
#pragma clang fp contract(off)
    const int tid  = blockIdx.x * 256 + threadIdx.x;
    const int ray  = tid >> 6;         // one wave per ray
    const int lane = tid & 63;         // samples s = lane + 64*k, k=0..7

    // Constants: computed in f64 exactly like Python, then cast to f32.
    const float STEP  = (float)((6.0 - 0.2) / 512.0);
    const float HALFS = (float)(((6.0 - 0.2) / 512.0) / 2.0);
    const float C415  = (float)(4.0 / 15.0);
    const float C512  = (float)(5.0 / 12.0);
    const double br   = 0.0008 * 2.0 / __builtin_sqrt(12.0);
    const float BR2   = (float)(br * br);
    const float DIVB  = 1.984375f;     // BOUND - half_grid, exact in f32

    const float* rp = rays_chunk + ray * 6;
    const float ox = rp[0], oy = rp[1], oz = rp[2];
    const float dx = rp[3], dy = rp[4], dz = rp[5];

    // Per-ray null_diag (matches: d_sq, d_mag_sq = max((x+y)+z, 1e-10))
    const float dsx = dx * dx, dsy = dy * dy, dsz = dz * dz;
    float dms = (dsx + dsy) + dsz;
    dms = fmaxf(dms, 1e-10f);
    const float nlx = 1.0f - dsx / dms;
    const float nly = 1.0f - dsy / dms;
    const float nlz = 1.0f - dsz / dms;

    const int sbase = ray * NSAMP;

    // Coalesced jitter loads (256B dense per instruction) + z values.
    float jloc[8], zv[8];
#pragma unroll
    for (int k = 0; k < 8; ++k) {
        const int s = lane + (k << 6);
        jloc[k] = __builtin_nontemporal_load(jitter + sbase + s);
        zv[k]   = 0.2f + STEP * ((float)s + jloc[k]);
    }

    const size_t OFF_VALID = (size_t)NRAYS * NSAMP * 4;             // 33554432
    const size_t OFF_Z     = OFF_VALID + (size_t)NRAYS * NSAMP;     // 41943040
    const size_t OFF_D     = OFF_Z     + (size_t)NRAYS * NSAMP;     // 50331648

#pragma unroll
    for (int k = 0; k < 8; ++k) {
        const int s   = lane + (k << 6);
        const int idx = sbase + s;
        const float z  = zv[k];
        const float t0 = z - HALFS;
        const float t1 = t0 + HALFS;
        const float mu = (t0 + t1) / 2.0f;
        const float hw = (t1 - t0) / 2.0f;
        const float mu2 = mu * mu;
        const float hw2 = hw * hw;
        const float hw4 = hw2 * hw2;
        const float denom  = 3.0f * mu2 + hw2;
        const float t_mean = mu + ((2.0f * mu) * hw2) / denom;
        const float inner  = 12.0f * mu2 - hw2;
        const float denom2 = denom * denom;
        const float t_var  = hw2 / 3.0f - (C415 * (hw4 * inner)) / denom2;
        const float r_var  = BR2 * ((mu2 / 4.0f + C512 * hw2) - (C415 * hw4) / denom);

        const float px = ox + dx * t_mean;
        const float py = oy + dy * t_mean;
        const float pz = oz + dz * t_mean;

        const bool outb = (px < -2.0f) | (px > 2.0f) |
                          (py < -2.0f) | (py > 2.0f) |
                          (pz < -2.0f) | (pz > 2.0f);

        const float vx = t_var * dsx + r_var * nlx;
        const float vy = t_var * dsy + r_var * nly;
        const float vz = t_var * dsz + r_var * nlz;
        const float vmax = fmaxf(fmaxf(vx, vy), vz);

        // voxel coords — exact reference op order
        const float cxn = fminf(fmaxf(px / DIVB, -1.0f), 1.0f);
        const float cyn = fminf(fmaxf(py / DIVB, -1.0f), 1.0f);
        const float czn = fminf(fmaxf(pz / DIVB, -1.0f), 1.0f);
        const float cfx = fminf(fmaxf((cxn + 1.0f) / 2.0f * 127.0f, 0.0f), 127.0f);
        const float cfy = fminf(fmaxf((cyn + 1.0f) / 2.0f * 127.0f, 0.0f), 127.0f);
        const float cfz = fminf(fmaxf((czn + 1.0f) / 2.0f * 127.0f, 0.0f), 127.0f);
        const unsigned int ux = (unsigned int)cfx;
        const unsigned int uy = (unsigned int)cfy;
        const unsigned int uz = (unsigned int)cfz;
        unsigned int m = expand_bits(ux) | (expand_bits(uy) << 1) | (expand_bits(uz) << 2);
        if (m > 2097151u) m = 2097151u;
        const int byte = bitfield[m >> 3];
        const bool alpha = ((byte >> (int)(m & 7u)) & 1) != 0;
        const bool valid = (!outb) && alpha;

        // dists: z[s+1] lives in lane+1 (same k); lane 63 takes lane 0 of k+1.
        // shfl passes exact bits -> dists is bit-identical to reference.
        float zn = __shfl_down(z, 1);
        const float znw = (k < 7) ? __shfl(zv[k + 1], 0) : 0.0f;
        if (lane == 63) zn = znw;
        const float dist = (s < NSAMP - 1) ? (zn - z) : 0.0f;

        floatx4 xw;
        xw[0] = px; xw[1] = py; xw[2] = pz; xw[3] = vmax;
        __builtin_nontemporal_store(xw, reinterpret_cast<floatx4*>(out + (size_t)idx * 4));
        __builtin_nontemporal_store(valid ? 1.0f : 0.0f, out + OFF_VALID + idx);
        __builtin_nontemporal_store(z,    out + OFF_Z + idx);
        __builtin_nontemporal_store(dist, out + OFF_D + idx);
    }
}

extern "C" void kernel_launch(void* const* d_in, const int* in_sizes, int n_in,
                              void* d_out, int out_size, void* d_ws, size_t ws_size,
                              hipStream_t stream) {
    const float* rays = (const float*)d_in[0];
    const float* jit  = (const float*)d_in[1];
    const int*   bf   = (const int*)d_in[2];
    float* out = (float*)d_out;

    const int total_threads = NRAYS * NSAMP / 8;   // 1,048,576
    dim3 grid(total_threads / 256), block(256);
    hipLaunchKernelGGL(ca_kernel, grid, block, 0, stream, rays, jit, bf, out);
}